// Round 1
// baseline (3351.695 us; speedup 1.0000x reference)
//
#include <hip/hip_runtime.h>

#define D_ 1024
#define T_ 1024
#define B_ 16

typedef short s16x8 __attribute__((ext_vector_type(8)));
typedef float f32x4 __attribute__((ext_vector_type(4)));

__device__ __forceinline__ unsigned short bf16_rne(float f){
  unsigned int u = __builtin_bit_cast(unsigned int, f);
  u += 0x7FFFu + ((u >> 16) & 1u);
  return (unsigned short)(u >> 16);
}
__device__ __forceinline__ float bf16_tof(unsigned short h){
  unsigned int u = ((unsigned int)h) << 16;
  return __builtin_bit_cast(float, u);
}
__device__ __forceinline__ float fsig(float x){ return 1.0f/(1.0f+__expf(-x)); }
__device__ __forceinline__ float ftanh(float x){ return 2.0f*fsig(2.0f*x)-1.0f; }

// MFMA wrapper robust to builtin operand type (short8 vs __bf16 x8)
template <typename V>
__device__ __forceinline__ auto mfma_try(V a, V b, f32x4 c, int)
    -> decltype(__builtin_amdgcn_mfma_f32_16x16x32_bf16(a, b, c, 0, 0, 0)) {
  return __builtin_amdgcn_mfma_f32_16x16x32_bf16(a, b, c, 0, 0, 0);
}
template <typename V>
__device__ __forceinline__ f32x4 mfma_try(V a, V b, f32x4 c, long) {
  typedef __bf16 bf16x8 __attribute__((ext_vector_type(8)));
  return __builtin_amdgcn_mfma_f32_16x16x32_bf16(
      __builtin_bit_cast(bf16x8, a), __builtin_bit_cast(bf16x8, b), c, 0, 0, 0);
}
__device__ __forceinline__ f32x4 MFMA(s16x8 a, s16x8 b, f32x4 c){
  return mfma_try(a, b, c, 0);
}

// ---------------- conversions ----------------

// x[b][t][d] f32 -> xtb[(t*16+b)][d] bf16
__global__ void k_conv_xtb(const float* __restrict__ x, unsigned short* __restrict__ xtb){
  int r = blockIdx.x; int b = r & 15, t = r >> 4;
  int d = threadIdx.x * 4;
  float4 v = *(const float4*)(x + ((size_t)b*T_ + t)*D_ + d);
  ushort4 o; o.x=bf16_rne(v.x); o.y=bf16_rne(v.y); o.z=bf16_rne(v.z); o.w=bf16_rne(v.w);
  *(ushort4*)(xtb + (size_t)r*D_ + d) = o;
}

__global__ void k_conv(const float* __restrict__ s, unsigned short* __restrict__ d, int n){
  int i = (blockIdx.x*256 + threadIdx.x)*4;
  if (i >= n) return;
  float4 v = *(const float4*)(s+i);
  ushort4 o; o.x=bf16_rne(v.x); o.y=bf16_rne(v.y); o.z=bf16_rne(v.z); o.w=bf16_rne(v.w);
  *(ushort4*)(d+i) = o;
}

// pack f32 row-major weight [rowOff+K, N] into MFMA B-fragment order (bf16)
// slot = ((nt*KT + kt)*64 + lane), holds B[kt*32+(lane>>4)*8+j][nt*16+(lane&15)], j=0..7
__global__ void k_fragprep(const float* __restrict__ w, int rowOff, int K, int Nsrc, int N,
                           unsigned short* __restrict__ dst){
  int KT = K >> 5;
  int slot = blockIdx.x*256 + threadIdx.x;
  int total = (N>>4) * KT * 64;
  if (slot >= total) return;
  int lane = slot & 63; int tmp = slot >> 6; int kt = tmp % KT; int nt = tmp / KT;
  int kbase = kt*32 + (lane>>4)*8; int col = nt*16 + (lane&15);
  unsigned short* o = dst + (size_t)slot*8;
  #pragma unroll
  for (int j=0;j<8;j++) o[j] = bf16_rne(w[(size_t)(rowOff + kbase + j)*Nsrc + col]);
}

// ---------------- small precompute ----------------

// ring-buffer window means at the 64 do2 points: bm[(e*16+b)][d] bf16
__global__ void k_bm(const float* __restrict__ x, unsigned short* __restrict__ bm){
  int e = blockIdx.x >> 4; int b = blockIdx.x & 15;
  int tc = 16*(e+1); int hi = tc-2; int lo = tc-33; if (lo < 0) lo = 0;
  const float* xb = x + (size_t)b*T_*D_;
  for (int d = threadIdx.x; d < D_; d += 256){
    float s = 0.f;
    for (int ss = lo; ss <= hi; ++ss) s += xb[(size_t)ss*D_ + d];
    bm[((size_t)(e*16+b))*D_ + d] = bf16_rne(s * (1.0f/32.0f));
  }
}

__global__ void k_beta(const unsigned short* __restrict__ bm, const float* __restrict__ w_t2b,
                       const float* __restrict__ b_t2b, float* __restrict__ beta){
  int r = blockIdx.x; int l = threadIdx.x;
  float s = 0.f;
  for (int d=l; d<D_; d+=64) s += bf16_tof(bm[(size_t)r*D_+d]) * w_t2b[d];
  #pragma unroll
  for (int off=32; off; off>>=1) s += __shfl_down(s, off);
  if (l==0) beta[r] = fsig(s + b_t2b[0]);
}

// bconst = b_fuse + b_t1r@Wf1 + b_t2r@Wf2 + b_t3r@Wf3
__global__ void k_bconst(const float* __restrict__ wf, const float* __restrict__ bf,
                         const float* __restrict__ b1, const float* __restrict__ b2,
                         const float* __restrict__ b3, float* __restrict__ bc){
  __shared__ float part[4][64];
  int n = blockIdx.x*64 + (threadIdx.x&63);
  int sl = threadIdx.x>>6;
  float s = 0.f;
  for (int k=sl*256; k<(sl+1)*256; ++k){
    s += b1[k]*wf[(size_t)k*1024+n] + b2[k]*wf[(size_t)(1024+k)*1024+n] + b3[k]*wf[(size_t)(2048+k)*1024+n];
  }
  part[sl][threadIdx.x&63] = s; __syncthreads();
  if (sl==0) bc[n] = bf[n] + part[0][threadIdx.x] + part[1][threadIdx.x] + part[2][threadIdx.x] + part[3][threadIdx.x];
}

// b2o = b_t2r@w_t3o + b_t3o ; b2n likewise
__global__ void k_b2(const float* __restrict__ b_t2r, const float* __restrict__ w3o,
                     const float* __restrict__ b3o, const float* __restrict__ w3n,
                     const float* __restrict__ b3n, float* __restrict__ b2o, float* __restrict__ b2n){
  __shared__ float part[2][128];
  int idx = threadIdx.x & 127; int sl = threadIdx.x >> 7;
  int mat = idx>>6, n = idx&63;
  const float* w = mat ? w3n : w3o;
  float s = 0.f;
  for (int k=sl*512; k<(sl+1)*512; ++k) s += b_t2r[k]*w[(size_t)k*64+n];
  part[sl][idx] = s; __syncthreads();
  if (sl==0){
    float r = part[0][idx] + part[1][idx] + (mat? b3n[n] : b3o[n]);
    if (mat) b2n[n] = r; else b2o[n] = r;
  }
}

// ---------------- generic bf16 MFMA GEMM ----------------
// C[M,N] = act(A[M,K](bf16,row-major) @ Bfrag + bias) ; N%64==0, K%32==0, M arbitrary
__global__ __launch_bounds__(256) void k_gemm(int M, int N, int K,
    const unsigned short* __restrict__ A, int lda,
    const unsigned short* __restrict__ Bf,
    const float* __restrict__ bias, int act,
    float* __restrict__ C, int ldc){
  int KT = K >> 5;
  int cb = blockIdx.x, rb = blockIdx.y;
  int w = threadIdx.x >> 6, l = threadIdx.x & 63;
  int rbase = rb*64 + w*16;
  int arow = rbase + (l & 15); if (arow >= M) arow = M-1;
  const unsigned short* Aptr = A + (size_t)arow*lda + ((l>>4)*8);
  const s16x8* B0 = (const s16x8*)Bf + ((size_t)(cb*4+0)*KT)*64 + l;
  const s16x8* B1 = (const s16x8*)Bf + ((size_t)(cb*4+1)*KT)*64 + l;
  const s16x8* B2 = (const s16x8*)Bf + ((size_t)(cb*4+2)*KT)*64 + l;
  const s16x8* B3 = (const s16x8*)Bf + ((size_t)(cb*4+3)*KT)*64 + l;
  f32x4 z = {0.f,0.f,0.f,0.f};
  f32x4 acc0=z, acc1=z, acc2=z, acc3=z;
  for (int kt=0; kt<KT; ++kt){
    s16x8 a = *(const s16x8*)(Aptr + (size_t)kt*32);
    acc0 = MFMA(a, B0[(size_t)kt*64], acc0);
    acc1 = MFMA(a, B1[(size_t)kt*64], acc1);
    acc2 = MFMA(a, B2[(size_t)kt*64], acc2);
    acc3 = MFMA(a, B3[(size_t)kt*64], acc3);
  }
  int r0 = (l>>4)*4;
  #pragma unroll
  for (int i=0;i<4;i++){
    f32x4 acc = i==0?acc0 : i==1?acc1 : i==2?acc2 : acc3;
    int col = (cb*4+i)*16 + (l&15);
    float bs = bias ? bias[col] : 0.0f;
    #pragma unroll
    for (int j=0;j<4;j++){
      int row = rbase + r0 + j;
      if (row < M){
        float vv = acc[j] + bs;
        if (act==1) vv = ftanh(vv);
        C[(size_t)row*ldc + col] = vv;
      }
    }
  }
}

// ---------------- tier2/tier3 trajectory (sequential, tiny) ----------------
__global__ __launch_bounds__(1024) void k_traj(
    const float* __restrict__ v, const float* __restrict__ beta,
    const float* __restrict__ w_b32, const float* __restrict__ b_b32,
    const float* __restrict__ w2o, const float* __restrict__ b2o,
    const float* __restrict__ w2n, const float* __restrict__ b2n,
    unsigned short* __restrict__ t2traj, unsigned short* __restrict__ t3traj){
  __shared__ float t2[16*128];
  __shared__ float t3[16*64];
  __shared__ float var3[16*64];
  __shared__ float zb[16*64];
  __shared__ float rb[16*64];
  int tid = threadIdx.x;
  for (int i=tid;i<2048;i+=1024){ t2[i]=0.f; t2traj[i]=0; }
  for (int i=tid;i<1024;i+=1024){
    int b=i>>6, n=i&63;
    t3[i]=0.f; var3[i]=1.f;
    t3traj[(size_t)b*128 + n] = 0;
    t3traj[(size_t)b*128 + 64 + n] = bf16_rne(1.f);
  }
  __syncthreads();
  for (int k=1;k<=64;k++){
    for (int i=tid;i<2048;i+=1024){
      int b=i>>7, n=i&127;
      float s=b_b32[n];
      for (int j=0;j<64;j++) s += t3[b*64+j]*w_b32[j*128+n];
      float t2b = t2[i] + ftanh(s);
      float bt = beta[(k-1)*16+b];
      float nv = t2b + bt*(v[(size_t)((k-1)*16+b)*128+n] - t2b);
      t2[i]=nv;
      t2traj[((size_t)k*16+b)*128+n] = bf16_rne(nv);
    }
    if ((k&7)==0){
      __syncthreads();
      for (int i=tid;i<2048;i+=1024){
        int mat=i>>10, b=(i>>6)&15, n=i&63;
        const float* w = mat? w2n : w2o;
        float s = mat? b2n[n] : b2o[n];
        for (int j=0;j<128;j++) s += t2[b*128+j]*w[j*64+n];
        if (mat){ float r = (s>20.f)? s : log1pf(__expf(s)); rb[b*64+n]=r+0.01f; }
        else zb[b*64+n]=s;
      }
      __syncthreads();
      for (int i=tid;i<1024;i+=1024){
        int b=i>>6, n=i&63;
        float sp = 0.99f*var3[i]+0.01f;
        float Kk = sp/(sp+rb[i]+1e-8f);
        float t3n_ = t3[i] + Kk*(zb[i]-t3[i]);
        float v3n = (1.f-Kk)*sp;
        t3[i]=t3n_; var3[i]=v3n;
        int jj=k>>3;
        t3traj[((size_t)jj*16+b)*128+n]    = bf16_rne(t3n_);
        t3traj[((size_t)jj*16+b)*128+64+n] = bf16_rne(v3n);
      }
      __syncthreads();
    }
  }
}

// ---------------- tier1 GRU recurrence (the critical path) ----------------
__global__ __launch_bounds__(512) void k_recur(
    const float* __restrict__ Pg, const float* __restrict__ Pc,
    const float* __restrict__ b21, // [65][16*256]
    const unsigned short* __restrict__ Wg2f, const unsigned short* __restrict__ Wc2f,
    unsigned short* __restrict__ traj){
  __shared__ float t1bf[4096];
  __shared__ float gbuf[4096];
  __shared__ float cbuf[4096];
  __shared__ unsigned short t1bb[4096]; // frag-order bf16 t1b
  int tid = threadIdx.x, w = tid>>6, l = tid&63;
  int mat = w&1, nb = w>>1;
  const s16x8* Bf = (const s16x8*)(mat? Wc2f : Wg2f);
  const float* P = mat? Pc : Pg;
  s16x8 bfr[4][8];
  #pragma unroll
  for (int i=0;i<4;i++){
    int nt = nb + 4*i;
    #pragma unroll
    for (int kt=0;kt<8;kt++) bfr[i][kt] = Bf[((size_t)nt*8+kt)*64 + l];
  }
  // init: t1b = 0 + b21[seg0]
  {
    int e0 = tid*8, b = e0>>8, n0 = e0&255;
    float4 v0 = *(const float4*)(b21+e0);
    float4 v1 = *(const float4*)(b21+e0+4);
    *(float4*)(t1bf+e0) = v0; *(float4*)(t1bf+e0+4) = v1;
    s16x8 hb;
    hb[0]=(short)bf16_rne(v0.x); hb[1]=(short)bf16_rne(v0.y); hb[2]=(short)bf16_rne(v0.z); hb[3]=(short)bf16_rne(v0.w);
    hb[4]=(short)bf16_rne(v1.x); hb[5]=(short)bf16_rne(v1.y); hb[6]=(short)bf16_rne(v1.z); hb[7]=(short)bf16_rne(v1.w);
    int kt=n0>>5, hi=(n0>>3)&3;
    *(s16x8*)(void*)(t1bb + (size_t)(kt*64+hi*16+b)*8) = hb;
  }
  int r0 = (l>>4)*4, cl = l&15;
  float pc_[4][4];
  #pragma unroll
  for (int i=0;i<4;i++){
    int col = (nb+4*i)*16+cl;
    #pragma unroll
    for (int j=0;j<4;j++) pc_[i][j] = P[(size_t)(r0+j)*256 + col];
  }
  __syncthreads();
  for (int t=0;t<1024;t++){
    // prefetch next step's P
    float pn_[4][4];
    int tn = t+1; if (tn>1023) tn=1023;
    #pragma unroll
    for (int i=0;i<4;i++){
      int col=(nb+4*i)*16+cl;
      #pragma unroll
      for (int j=0;j<4;j++) pn_[i][j] = P[((size_t)tn*16 + r0 + j)*256 + col];
    }
    f32x4 z = {0.f,0.f,0.f,0.f};
    f32x4 a0=z,a1=z,a2=z,a3=z;
    #pragma unroll
    for (int kt=0;kt<8;kt++){
      s16x8 af = *(const s16x8*)(void*)(t1bb + (size_t)(kt*64+l)*8);
      a0 = MFMA(af, bfr[0][kt], a0);
      a1 = MFMA(af, bfr[1][kt], a1);
      a2 = MFMA(af, bfr[2][kt], a2);
      a3 = MFMA(af, bfr[3][kt], a3);
    }
    float* ob = mat? cbuf : gbuf;
    #pragma unroll
    for (int i=0;i<4;i++){
      f32x4 ac = i==0?a0 : i==1?a1 : i==2?a2 : a3;
      int col=(nb+4*i)*16+cl;
      #pragma unroll
      for (int j=0;j<4;j++){
        float vv = ac[j] + pc_[i][j];
        vv = mat? ftanh(vv) : fsig(vv);
        ob[(r0+j)*256 + col] = vv;
      }
    }
    __syncthreads();
    {
      int e0=tid*8, b=e0>>8, n0=e0&255;
      float4 tb0 = *(const float4*)(t1bf+e0), tb1 = *(const float4*)(t1bf+e0+4);
      float4 g0 = *(const float4*)(gbuf+e0), g1 = *(const float4*)(gbuf+e0+4);
      float4 c0 = *(const float4*)(cbuf+e0), c1 = *(const float4*)(cbuf+e0+4);
      float nt1[8];
      nt1[0]=g0.x*tb0.x+(1.f-g0.x)*c0.x; nt1[1]=g0.y*tb0.y+(1.f-g0.y)*c0.y;
      nt1[2]=g0.z*tb0.z+(1.f-g0.z)*c0.z; nt1[3]=g0.w*tb0.w+(1.f-g0.w)*c0.w;
      nt1[4]=g1.x*tb1.x+(1.f-g1.x)*c1.x; nt1[5]=g1.y*tb1.y+(1.f-g1.y)*c1.y;
      nt1[6]=g1.z*tb1.z+(1.f-g1.z)*c1.z; nt1[7]=g1.w*tb1.w+(1.f-g1.w)*c1.w;
      s16x8 ht;
      #pragma unroll
      for (int q=0;q<8;q++) ht[q]=(short)bf16_rne(nt1[q]);
      *(s16x8*)(void*)(traj + ((size_t)(t*16+b))*256 + n0) = ht;
      const float* bn = b21 + (size_t)((t+1)>>4)*4096 + e0;
      float4 bn0 = *(const float4*)(bn), bn1 = *(const float4*)(bn+4);
      float t1n[8];
      t1n[0]=nt1[0]+bn0.x; t1n[1]=nt1[1]+bn0.y; t1n[2]=nt1[2]+bn0.z; t1n[3]=nt1[3]+bn0.w;
      t1n[4]=nt1[4]+bn1.x; t1n[5]=nt1[5]+bn1.y; t1n[6]=nt1[6]+bn1.z; t1n[7]=nt1[7]+bn1.w;
      *(float4*)(t1bf+e0)   = make_float4(t1n[0],t1n[1],t1n[2],t1n[3]);
      *(float4*)(t1bf+e0+4) = make_float4(t1n[4],t1n[5],t1n[6],t1n[7]);
      s16x8 hb;
      #pragma unroll
      for (int q=0;q<8;q++) hb[q]=(short)bf16_rne(t1n[q]);
      int kt=n0>>5, hi=(n0>>3)&3;
      *(s16x8*)(void*)(t1bb + (size_t)(kt*64+hi*16+b)*8) = hb;
    }
    #pragma unroll
    for (int i=0;i<4;i++)
      #pragma unroll
      for (int j=0;j<4;j++) pc_[i][j]=pn_[i][j];
    __syncthreads();
  }
}

// ---------------- fused1 GEMM + segment adds + LayerNorm + output ----------------
__global__ __launch_bounds__(1024) void k_final(
    const unsigned short* __restrict__ traj, const unsigned short* __restrict__ Bf,
    const float* __restrict__ bconst, const float* __restrict__ f2seg, const float* __restrict__ f3seg,
    const float* __restrict__ ln_g, const float* __restrict__ ln_b, float* __restrict__ out){
  __shared__ float buf[16*1024];
  __shared__ float mu[16];
  __shared__ float rs[16];
  int t = blockIdx.x, tid = threadIdx.x, w = tid>>6, l = tid&63;
  const unsigned short* Ab = traj + ((size_t)t*16 + (l&15))*256 + (l>>4)*8;
  const s16x8* Bp = (const s16x8*)Bf;
  f32x4 z = {0.f,0.f,0.f,0.f};
  f32x4 ac[4]; ac[0]=z; ac[1]=z; ac[2]=z; ac[3]=z;
  #pragma unroll
  for (int kt=0;kt<8;kt++){
    s16x8 a = *(const s16x8*)(Ab + kt*32);
    #pragma unroll
    for (int i=0;i<4;i++){
      int nt = w*4+i;
      ac[i] = MFMA(a, Bp[((size_t)nt*8+kt)*64+l], ac[i]);
    }
  }
  int tc = t+1, s2 = tc>>4, s3 = tc>>7;
  int r0 = (l>>4)*4, cl = l&15;
  #pragma unroll
  for (int i=0;i<4;i++){
    int col = (w*4+i)*16+cl;
    #pragma unroll
    for (int j=0;j<4;j++){
      int b = r0+j;
      buf[b*1024+col] = ac[i][j] + bconst[col]
        + f2seg[((size_t)s2*16+b)*1024+col] + f3seg[((size_t)s3*16+b)*1024+col];
    }
  }
  __syncthreads();
  {
    float s=0.f, q=0.f;
    #pragma unroll
    for (int i=0;i<16;i++){ float xv = buf[w*1024 + l + 64*i]; s+=xv; q+=xv*xv; }
    #pragma unroll
    for (int off=32;off;off>>=1){ s += __shfl_down(s,off); q += __shfl_down(q,off); }
    if (l==0){ float m = s*(1.f/1024.f); float var = q*(1.f/1024.f) - m*m; mu[w]=m; rs[w]=rsqrtf(var+1e-5f); }
  }
  __syncthreads();
  {
    int b = tid>>6, d0 = tid&63;
    float m = mu[b], r = rs[b];
    size_t ob = ((size_t)b*1024 + t)*1024;
    #pragma unroll
    for (int i=0;i<16;i++){
      int d = d0 + 64*i;
      out[ob + d] = (buf[b*1024+d]-m)*r*ln_g[d] + ln_b[d];
    }
  }
}

// ---------------- launcher ----------------
extern "C" void kernel_launch(void* const* d_in, const int* in_sizes, int n_in,
                              void* d_out, int out_size, void* d_ws, size_t ws_size,
                              hipStream_t stream){
  const float* x     = (const float*)d_in[0];
  const float* w_t1g = (const float*)d_in[1];
  const float* b_t1g = (const float*)d_in[2];
  const float* w_t1c = (const float*)d_in[3];
  const float* b_t1c = (const float*)d_in[4];
  const float* w_t1r = (const float*)d_in[5];
  const float* b_t1r = (const float*)d_in[6];
  const float* w_t2v = (const float*)d_in[7];
  const float* b_t2v = (const float*)d_in[8];
  const float* w_t2b = (const float*)d_in[9];
  const float* b_t2b = (const float*)d_in[10];
  const float* w_t2r = (const float*)d_in[11];
  const float* b_t2r = (const float*)d_in[12];
  const float* w_t3o = (const float*)d_in[13];
  const float* b_t3o = (const float*)d_in[14];
  const float* w_t3n = (const float*)d_in[15];
  const float* b_t3n = (const float*)d_in[16];
  const float* w_t3r = (const float*)d_in[17];
  const float* b_t3r = (const float*)d_in[18];
  const float* w_b32 = (const float*)d_in[19];
  const float* b_b32 = (const float*)d_in[20];
  const float* w_b21 = (const float*)d_in[21];
  const float* b_b21 = (const float*)d_in[22];
  const float* w_fuse= (const float*)d_in[23];
  const float* b_fuse= (const float*)d_in[24];
  const float* ln_g  = (const float*)d_in[25];
  const float* ln_b  = (const float*)d_in[26];
  float* out = (float*)d_out;
  (void)in_sizes; (void)n_in; (void)out_size; (void)ws_size;

  char* base = (char*)d_ws;
  size_t off = 0;
  auto alloc = [&](size_t bytes) -> void* {
    void* p = base + off;
    off += (bytes + 255) & ~(size_t)255;
    return p;
  };
  unsigned short* xtb   = (unsigned short*)alloc((size_t)B_*T_*D_*2);
  float* Pg             = (float*)alloc((size_t)B_*T_*256*4);
  float* Pc             = (float*)alloc((size_t)B_*T_*256*4);
  unsigned short* traj1 = (unsigned short*)alloc((size_t)B_*T_*256*2);
  unsigned short* bm    = (unsigned short*)alloc((size_t)1024*1024*2);
  float* v      = (float*)alloc((size_t)1024*128*4);
  float* beta   = (float*)alloc(1024*4);
  float* wr1f   = (float*)alloc((size_t)256*1024*4);
  float* wr2f   = (float*)alloc((size_t)128*1024*4);
  float* wr3f   = (float*)alloc((size_t)128*1024*4);
  float* w2o    = (float*)alloc(128*64*4);
  float* w2n    = (float*)alloc(128*64*4);
  float* b2o    = (float*)alloc(64*4);
  float* b2n    = (float*)alloc(64*4);
  float* bconst = (float*)alloc(1024*4);
  unsigned short* t2traj = (unsigned short*)alloc((size_t)1040*128*2);
  unsigned short* t3traj = (unsigned short*)alloc((size_t)144*128*2);
  float* b21seg = (float*)alloc((size_t)1040*256*4);
  float* f2seg  = (float*)alloc((size_t)1040*1024*4);
  float* f3seg  = (float*)alloc((size_t)144*1024*4);
  unsigned short* w_t1r_bf = (unsigned short*)alloc((size_t)256*1024*2);
  unsigned short* w_t2r_bf = (unsigned short*)alloc((size_t)128*1024*2);
  unsigned short* w_t3r_bf = (unsigned short*)alloc((size_t)128*1024*2);
  unsigned short* wg1f  = (unsigned short*)alloc((size_t)1024*256*2);
  unsigned short* wg2f  = (unsigned short*)alloc((size_t)256*256*2);
  unsigned short* wc1f  = (unsigned short*)alloc((size_t)1024*256*2);
  unsigned short* wc2f  = (unsigned short*)alloc((size_t)256*256*2);
  unsigned short* wtvf  = (unsigned short*)alloc((size_t)1024*128*2);
  unsigned short* wb21f = (unsigned short*)alloc((size_t)128*256*2);
  unsigned short* wf1f  = (unsigned short*)alloc((size_t)1024*1024*2);
  unsigned short* wf2f  = (unsigned short*)alloc((size_t)1024*1024*2);
  unsigned short* wf3f  = (unsigned short*)alloc((size_t)1024*1024*2);
  unsigned short* w3of  = (unsigned short*)alloc((size_t)1024*64*2);
  unsigned short* w3nf  = (unsigned short*)alloc((size_t)1024*64*2);
  unsigned short* wr1ff = (unsigned short*)alloc((size_t)256*1024*2);
  unsigned short* wr2ff = (unsigned short*)alloc((size_t)128*1024*2);
  unsigned short* wr3ff = (unsigned short*)alloc((size_t)128*1024*2);

  // conversions / fragment packs
  k_conv_xtb<<<dim3(B_*T_), dim3(256), 0, stream>>>(x, xtb);
  k_conv<<<dim3(256), dim3(256), 0, stream>>>(w_t1r, w_t1r_bf, 256*1024);
  k_conv<<<dim3(128), dim3(256), 0, stream>>>(w_t2r, w_t2r_bf, 128*1024);
  k_conv<<<dim3(128), dim3(256), 0, stream>>>(w_t3r, w_t3r_bf, 128*1024);
  k_fragprep<<<dim3(128), dim3(256), 0, stream>>>(w_t1g, 0, 1024, 256, 256, wg1f);
  k_fragprep<<<dim3(32),  dim3(256), 0, stream>>>(w_t1g, 1024, 256, 256, 256, wg2f);
  k_fragprep<<<dim3(128), dim3(256), 0, stream>>>(w_t1c, 0, 1024, 256, 256, wc1f);
  k_fragprep<<<dim3(32),  dim3(256), 0, stream>>>(w_t1c, 1024, 256, 256, 256, wc2f);
  k_fragprep<<<dim3(64),  dim3(256), 0, stream>>>(w_t2v, 0, 1024, 128, 128, wtvf);
  k_fragprep<<<dim3(16),  dim3(256), 0, stream>>>(w_b21, 0, 128, 256, 256, wb21f);
  k_fragprep<<<dim3(512), dim3(256), 0, stream>>>(w_fuse, 0,    1024, 1024, 1024, wf1f);
  k_fragprep<<<dim3(512), dim3(256), 0, stream>>>(w_fuse, 1024, 1024, 1024, 1024, wf2f);
  k_fragprep<<<dim3(512), dim3(256), 0, stream>>>(w_fuse, 2048, 1024, 1024, 1024, wf3f);
  k_fragprep<<<dim3(32),  dim3(256), 0, stream>>>(w_t3o, 0, 1024, 64, 64, w3of);
  k_fragprep<<<dim3(32),  dim3(256), 0, stream>>>(w_t3n, 0, 1024, 64, 64, w3nf);
  // window means + beta
  k_bm<<<dim3(1024), dim3(256), 0, stream>>>(x, bm);
  k_beta<<<dim3(1024), dim3(64), 0, stream>>>(bm, w_t2b, b_t2b, beta);
  // parallel GEMMs
  k_gemm<<<dim3(4,256), dim3(256), 0, stream>>>(16384,256,1024, xtb,1024, wg1f, b_t1g, 0, Pg, 256);
  k_gemm<<<dim3(4,256), dim3(256), 0, stream>>>(16384,256,1024, xtb,1024, wc1f, b_t1c, 0, Pc, 256);
  k_gemm<<<dim3(2,16),  dim3(256), 0, stream>>>(1024,128,1024, bm,1024, wtvf, b_t2v, 0, v, 128);
  k_gemm<<<dim3(16,4),  dim3(256), 0, stream>>>(256,1024,1024, w_t1r_bf,1024, wf1f, nullptr, 0, wr1f, 1024);
  k_gemm<<<dim3(16,2),  dim3(256), 0, stream>>>(128,1024,1024, w_t2r_bf,1024, wf2f, nullptr, 0, wr2f, 1024);
  k_gemm<<<dim3(16,2),  dim3(256), 0, stream>>>(128,1024,1024, w_t3r_bf,1024, wf3f, nullptr, 0, wr3f, 1024);
  k_gemm<<<dim3(1,2),   dim3(256), 0, stream>>>(128,64,1024, w_t2r_bf,1024, w3of, nullptr, 0, w2o, 64);
  k_gemm<<<dim3(1,2),   dim3(256), 0, stream>>>(128,64,1024, w_t2r_bf,1024, w3nf, nullptr, 0, w2n, 64);
  // bias folds
  k_bconst<<<dim3(16), dim3(256), 0, stream>>>(w_fuse, b_fuse, b_t1r, b_t2r, b_t3r, bconst);
  k_b2<<<dim3(1), dim3(256), 0, stream>>>(b_t2r, w_t3o, b_t3o, w_t3n, b_t3n, b2o, b2n);
  // fragment packs of folded weights
  k_fragprep<<<dim3(128), dim3(256), 0, stream>>>(wr1f, 0, 256, 1024, 1024, wr1ff);
  k_fragprep<<<dim3(64),  dim3(256), 0, stream>>>(wr2f, 0, 128, 1024, 1024, wr2ff);
  k_fragprep<<<dim3(64),  dim3(256), 0, stream>>>(wr3f, 0, 128, 1024, 1024, wr3ff);
  // tier2/3 trajectory
  k_traj<<<dim3(1), dim3(1024), 0, stream>>>(v, beta, w_b32, b_b32, w2o, b2o, w2n, b2n, t2traj, t3traj);
  // segment GEMMs
  k_gemm<<<dim3(4,17),  dim3(256), 0, stream>>>(1040,256,128, t2traj,128, wb21f, b_b21, 1, b21seg, 256);
  k_gemm<<<dim3(16,17), dim3(256), 0, stream>>>(1040,1024,128, t2traj,128, wr2ff, nullptr, 0, f2seg, 1024);
  k_gemm<<<dim3(16,3),  dim3(256), 0, stream>>>(144,1024,128, t3traj,128, wr3ff, nullptr, 0, f3seg, 1024);
  // tier1 recurrence (critical path)
  k_recur<<<dim3(1), dim3(512), 0, stream>>>(Pg, Pc, b21seg, wg2f, wc2f, traj1);
  // fused output + LN
  k_final<<<dim3(1024), dim3(1024), 0, stream>>>(traj1, wr1ff, bconst, f2seg, f3seg, ln_g, ln_b, out);
}

// Round 3
// 1663.027 us; speedup vs baseline: 2.0154x; 2.0154x over previous
//
#include <hip/hip_runtime.h>

#define D_ 1024
#define T_ 1024
#define B_ 16

typedef short s16x8 __attribute__((ext_vector_type(8)));
typedef float f32x4 __attribute__((ext_vector_type(4)));

__device__ __forceinline__ unsigned short bf16_rne(float f){
  unsigned int u = __builtin_bit_cast(unsigned int, f);
  u += 0x7FFFu + ((u >> 16) & 1u);
  return (unsigned short)(u >> 16);
}
__device__ __forceinline__ float bf16_tof(unsigned short h){
  unsigned int u = ((unsigned int)h) << 16;
  return __builtin_bit_cast(float, u);
}
__device__ __forceinline__ float fsig(float x){ return 1.0f/(1.0f+__expf(-x)); }
__device__ __forceinline__ float ftanh(float x){ return 2.0f*fsig(2.0f*x)-1.0f; }

// MFMA wrapper robust to builtin operand type (short8 vs __bf16 x8)
template <typename V>
__device__ __forceinline__ auto mfma_try(V a, V b, f32x4 c, int)
    -> decltype(__builtin_amdgcn_mfma_f32_16x16x32_bf16(a, b, c, 0, 0, 0)) {
  return __builtin_amdgcn_mfma_f32_16x16x32_bf16(a, b, c, 0, 0, 0);
}
template <typename V>
__device__ __forceinline__ f32x4 mfma_try(V a, V b, f32x4 c, long) {
  typedef __bf16 bf16x8 __attribute__((ext_vector_type(8)));
  return __builtin_amdgcn_mfma_f32_16x16x32_bf16(
      __builtin_bit_cast(bf16x8, a), __builtin_bit_cast(bf16x8, b), c, 0, 0, 0);
}
__device__ __forceinline__ f32x4 MFMA(s16x8 a, s16x8 b, f32x4 c){
  return mfma_try(a, b, c, 0);
}

// ---------------- conversions ----------------

// x[b][t][d] f32 -> xtb[(t*16+b)][d] bf16
__global__ void k_conv_xtb(const float* __restrict__ x, unsigned short* __restrict__ xtb){
  int r = blockIdx.x; int b = r & 15, t = r >> 4;
  int d = threadIdx.x * 4;
  float4 v = *(const float4*)(x + ((size_t)b*T_ + t)*D_ + d);
  ushort4 o; o.x=bf16_rne(v.x); o.y=bf16_rne(v.y); o.z=bf16_rne(v.z); o.w=bf16_rne(v.w);
  *(ushort4*)(xtb + (size_t)r*D_ + d) = o;
}

__global__ void k_conv(const float* __restrict__ s, unsigned short* __restrict__ d, int n){
  int i = (blockIdx.x*256 + threadIdx.x)*4;
  if (i >= n) return;
  float4 v = *(const float4*)(s+i);
  ushort4 o; o.x=bf16_rne(v.x); o.y=bf16_rne(v.y); o.z=bf16_rne(v.z); o.w=bf16_rne(v.w);
  *(ushort4*)(d+i) = o;
}

// pack f32 row-major weight [rowOff+K, N] into MFMA B-fragment order (bf16)
// slot = ((nt*KT + kt)*64 + lane), holds B[kt*32+(lane>>4)*8+j][nt*16+(lane&15)], j=0..7
__global__ void k_fragprep(const float* __restrict__ w, int rowOff, int K, int Nsrc, int N,
                           unsigned short* __restrict__ dst){
  int KT = K >> 5;
  int slot = blockIdx.x*256 + threadIdx.x;
  int total = (N>>4) * KT * 64;
  if (slot >= total) return;
  int lane = slot & 63; int tmp = slot >> 6; int kt = tmp % KT; int nt = tmp / KT;
  int kbase = kt*32 + (lane>>4)*8; int col = nt*16 + (lane&15);
  unsigned short* o = dst + (size_t)slot*8;
  #pragma unroll
  for (int j=0;j<8;j++) o[j] = bf16_rne(w[(size_t)(rowOff + kbase + j)*Nsrc + col]);
}

// ---------------- small precompute ----------------

// ring-buffer window means at the 64 do2 points: bm[(e*16+b)][d] bf16
__global__ void k_bm(const float* __restrict__ x, unsigned short* __restrict__ bm){
  int e = blockIdx.x >> 4; int b = blockIdx.x & 15;
  int tc = 16*(e+1); int hi = tc-2; int lo = tc-33; if (lo < 0) lo = 0;
  const float* xb = x + (size_t)b*T_*D_;
  for (int d = threadIdx.x; d < D_; d += 256){
    float s = 0.f;
    for (int ss = lo; ss <= hi; ++ss) s += xb[(size_t)ss*D_ + d];
    bm[((size_t)(e*16+b))*D_ + d] = bf16_rne(s * (1.0f/32.0f));
  }
}

__global__ void k_beta(const unsigned short* __restrict__ bm, const float* __restrict__ w_t2b,
                       const float* __restrict__ b_t2b, float* __restrict__ beta){
  int r = blockIdx.x; int l = threadIdx.x;
  float s = 0.f;
  for (int d=l; d<D_; d+=64) s += bf16_tof(bm[(size_t)r*D_+d]) * w_t2b[d];
  #pragma unroll
  for (int off=32; off; off>>=1) s += __shfl_down(s, off);
  if (l==0) beta[r] = fsig(s + b_t2b[0]);
}

// bconst = b_fuse + b_t1r@Wf1 + b_t2r@Wf2 + b_t3r@Wf3
__global__ void k_bconst(const float* __restrict__ wf, const float* __restrict__ bf,
                         const float* __restrict__ b1, const float* __restrict__ b2,
                         const float* __restrict__ b3, float* __restrict__ bc){
  __shared__ float part[4][64];
  int n = blockIdx.x*64 + (threadIdx.x&63);
  int sl = threadIdx.x>>6;
  float s = 0.f;
  for (int k=sl*256; k<(sl+1)*256; ++k){
    s += b1[k]*wf[(size_t)k*1024+n] + b2[k]*wf[(size_t)(1024+k)*1024+n] + b3[k]*wf[(size_t)(2048+k)*1024+n];
  }
  part[sl][threadIdx.x&63] = s; __syncthreads();
  if (sl==0) bc[n] = bf[n] + part[0][threadIdx.x] + part[1][threadIdx.x] + part[2][threadIdx.x] + part[3][threadIdx.x];
}

// b2o = b_t2r@w_t3o + b_t3o ; b2n likewise
__global__ void k_b2(const float* __restrict__ b_t2r, const float* __restrict__ w3o,
                     const float* __restrict__ b3o, const float* __restrict__ w3n,
                     const float* __restrict__ b3n, float* __restrict__ b2o, float* __restrict__ b2n){
  __shared__ float part[2][128];
  int idx = threadIdx.x & 127; int sl = threadIdx.x >> 7;
  int mat = idx>>6, n = idx&63;
  const float* w = mat ? w3n : w3o;
  float s = 0.f;
  for (int k=sl*512; k<(sl+1)*512; ++k) s += b_t2r[k]*w[(size_t)k*64+n];
  part[sl][idx] = s; __syncthreads();
  if (sl==0){
    float r = part[0][idx] + part[1][idx] + (mat? b3n[n] : b3o[n]);
    if (mat) b2n[n] = r; else b2o[n] = r;
  }
}

// ---------------- generic bf16 MFMA GEMM ----------------
// C[M,N] = act(A[M,K](bf16,row-major) @ Bfrag + bias) ; N%64==0, K%32==0, M arbitrary
__global__ __launch_bounds__(256) void k_gemm(int M, int N, int K,
    const unsigned short* __restrict__ A, int lda,
    const unsigned short* __restrict__ Bf,
    const float* __restrict__ bias, int act,
    float* __restrict__ C, int ldc){
  int KT = K >> 5;
  int cb = blockIdx.x, rb = blockIdx.y;
  int w = threadIdx.x >> 6, l = threadIdx.x & 63;
  int rbase = rb*64 + w*16;
  int arow = rbase + (l & 15); if (arow >= M) arow = M-1;
  const unsigned short* Aptr = A + (size_t)arow*lda + ((l>>4)*8);
  const s16x8* B0 = (const s16x8*)Bf + ((size_t)(cb*4+0)*KT)*64 + l;
  const s16x8* B1 = (const s16x8*)Bf + ((size_t)(cb*4+1)*KT)*64 + l;
  const s16x8* B2 = (const s16x8*)Bf + ((size_t)(cb*4+2)*KT)*64 + l;
  const s16x8* B3 = (const s16x8*)Bf + ((size_t)(cb*4+3)*KT)*64 + l;
  f32x4 z = {0.f,0.f,0.f,0.f};
  f32x4 acc0=z, acc1=z, acc2=z, acc3=z;
  for (int kt=0; kt<KT; ++kt){
    s16x8 a = *(const s16x8*)(Aptr + (size_t)kt*32);
    acc0 = MFMA(a, B0[(size_t)kt*64], acc0);
    acc1 = MFMA(a, B1[(size_t)kt*64], acc1);
    acc2 = MFMA(a, B2[(size_t)kt*64], acc2);
    acc3 = MFMA(a, B3[(size_t)kt*64], acc3);
  }
  int r0 = (l>>4)*4;
  #pragma unroll
  for (int i=0;i<4;i++){
    f32x4 acc = i==0?acc0 : i==1?acc1 : i==2?acc2 : acc3;
    int col = (cb*4+i)*16 + (l&15);
    float bs = bias ? bias[col] : 0.0f;
    #pragma unroll
    for (int j=0;j<4;j++){
      int row = rbase + r0 + j;
      if (row < M){
        float vv = acc[j] + bs;
        if (act==1) vv = ftanh(vv);
        C[(size_t)row*ldc + col] = vv;
      }
    }
  }
}

// ---------------- tier2/tier3 trajectory (sequential, tiny) ----------------
__global__ __launch_bounds__(1024) void k_traj(
    const float* __restrict__ v, const float* __restrict__ beta,
    const float* __restrict__ w_b32, const float* __restrict__ b_b32,
    const float* __restrict__ w2o, const float* __restrict__ b2o,
    const float* __restrict__ w2n, const float* __restrict__ b2n,
    unsigned short* __restrict__ t2traj, unsigned short* __restrict__ t3traj){
  __shared__ float t2[16*128];
  __shared__ float t3[16*64];
  __shared__ float var3[16*64];
  __shared__ float zb[16*64];
  __shared__ float rb[16*64];
  int tid = threadIdx.x;
  for (int i=tid;i<2048;i+=1024){ t2[i]=0.f; t2traj[i]=0; }
  for (int i=tid;i<1024;i+=1024){
    int b=i>>6, n=i&63;
    t3[i]=0.f; var3[i]=1.f;
    t3traj[(size_t)b*128 + n] = 0;
    t3traj[(size_t)b*128 + 64 + n] = bf16_rne(1.f);
  }
  __syncthreads();
  for (int k=1;k<=64;k++){
    for (int i=tid;i<2048;i+=1024){
      int b=i>>7, n=i&127;
      float s=b_b32[n];
      for (int j=0;j<64;j++) s += t3[b*64+j]*w_b32[j*128+n];
      float t2b = t2[i] + ftanh(s);
      float bt = beta[(k-1)*16+b];
      float nv = t2b + bt*(v[(size_t)((k-1)*16+b)*128+n] - t2b);
      t2[i]=nv;
      t2traj[((size_t)k*16+b)*128+n] = bf16_rne(nv);
    }
    if ((k&7)==0){
      __syncthreads();
      for (int i=tid;i<2048;i+=1024){
        int mat=i>>10, b=(i>>6)&15, n=i&63;
        const float* w = mat? w2n : w2o;
        float s = mat? b2n[n] : b2o[n];
        for (int j=0;j<128;j++) s += t2[b*128+j]*w[j*64+n];
        if (mat){ float r = (s>20.f)? s : log1pf(__expf(s)); rb[b*64+n]=r+0.01f; }
        else zb[b*64+n]=s;
      }
      __syncthreads();
      for (int i=tid;i<1024;i+=1024){
        int b=i>>6, n=i&63;
        float sp = 0.99f*var3[i]+0.01f;
        float Kk = sp/(sp+rb[i]+1e-8f);
        float t3n_ = t3[i] + Kk*(zb[i]-t3[i]);
        float v3n = (1.f-Kk)*sp;
        t3[i]=t3n_; var3[i]=v3n;
        int jj=k>>3;
        t3traj[((size_t)jj*16+b)*128+n]    = bf16_rne(t3n_);
        t3traj[((size_t)jj*16+b)*128+64+n] = bf16_rne(v3n);
      }
      __syncthreads();
    }
  }
}

// ---------------- tier1 GRU recurrence (the critical path) ----------------
// One block per batch row. 8 waves; wave w owns output columns [32w, 32w+32).
// State (256 bf16) double-buffered in LDS; t1b f32 master lives in the owner
// lane's register. Weights (both matrices) register-resident. One raw
// s_barrier per step (lgkmcnt only) so traj stores / P prefetch stay in flight.
__global__ __launch_bounds__(512) void k_recur(
    const float* __restrict__ Pg, const float* __restrict__ Pc,
    const float* __restrict__ b21, // [65][16][256]
    const unsigned short* __restrict__ Wg2f, const unsigned short* __restrict__ Wc2f,
    unsigned short* __restrict__ traj){
  __shared__ unsigned short sbuf[2][256];
  int b = blockIdx.x;
  int tid = threadIdx.x, w = tid>>6, l = tid&63;
  int hi = l>>4, cl = l&15;
  const s16x8* Bg = (const s16x8*)Wg2f;
  const s16x8* Bc = (const s16x8*)Wc2f;
  s16x8 bg0[8], bg1[8], bc0[8], bc1[8];
  #pragma unroll
  for (int kt=0;kt<8;kt++){
    bg0[kt] = Bg[((size_t)(2*w)*8  +kt)*64 + l];
    bg1[kt] = Bg[((size_t)(2*w+1)*8+kt)*64 + l];
    bc0[kt] = Bc[((size_t)(2*w)*8  +kt)*64 + l];
    bc1[kt] = Bc[((size_t)(2*w+1)*8+kt)*64 + l];
  }
  // epilogue ownership: lanes hi=0 handle tile 2w, hi=1 handle tile 2w+1
  bool owner = (hi < 2);
  int nt = 2*w + hi;
  int n  = nt*16 + cl;       // column owned (only meaningful when owner)
  if (!owner) n = 2*w*16 + cl; // harmless valid index for inactive lanes
  float t1b = 0.f;
  float pgN=0.f, pcN=0.f, bbN=0.f;
  if (owner){
    bbN = b21[((size_t)b)*256 + n];            // seg 0 (consumed at t=0: seg((0+1)>>4)=0)
    t1b = bbN;                                  // tier1=0 + bias21 (state entering t=0)
    pgN = Pg[((size_t)b)*256 + n];              // t=0
    pcN = Pc[((size_t)b)*256 + n];
    sbuf[0][n] = bf16_rne(t1b);
  }
  asm volatile("s_waitcnt lgkmcnt(0)\ns_barrier" ::: "memory");
  for (int t=0;t<1024;t++){
    float pg = pgN, pc = pcN, bb = bbN;
    // prefetch next step's P / b21 (consumed at iteration t+1).
    // bb consumed at iter t+1 forms state entering iter t+2 -> seg ((t+2)>>4).
    // (Round-2 bug: used (t+1)>>4 here -> bias one segment stale at t=15,31,...)
    int tn = (t+1 < 1024) ? (t+1) : 1023;
    if (owner){
      pgN = Pg[((size_t)(tn*16+b))*256 + n];
      pcN = Pc[((size_t)(tn*16+b))*256 + n];
      bbN = b21[(((size_t)((t+2)>>4))*16 + b)*256 + n];
    }
    const unsigned short* sb = sbuf[t&1];
    f32x4 z = {0.f,0.f,0.f,0.f};
    f32x4 ag0=z, ag1=z, ac0=z, ac1=z;
    #pragma unroll
    for (int kt=0;kt<8;kt++){
      // broadcast read: all 16 lanes of a hi-group read the same 16B of state
      s16x8 a = *(const s16x8*)(sb + kt*32 + hi*8);
      ag0 = MFMA(a, bg0[kt], ag0);
      ag1 = MFMA(a, bg1[kt], ag1);
      ac0 = MFMA(a, bc0[kt], ac0);
      ac1 = MFMA(a, bc1[kt], ac1);
    }
    if (owner){
      // all A rows are identical, so acc[0] holds the output for col=cl
      float gacc = (hi==0)? ag0[0] : ag1[0];
      float cacc = (hi==0)? ac0[0] : ac1[0];
      float g = fsig(gacc + pg);
      float c = ftanh(cacc + pc);
      float t1n = g*t1b + (1.f-g)*c;
      traj[((size_t)(t*16+b))*256 + n] = bf16_rne(t1n);
      t1b = t1n + bb;
      sbuf[(t+1)&1][n] = bf16_rne(t1b);
    }
    asm volatile("s_waitcnt lgkmcnt(0)\ns_barrier" ::: "memory");
  }
}

// ---------------- fused1 GEMM + segment adds + LayerNorm + output ----------------
__global__ __launch_bounds__(1024) void k_final(
    const unsigned short* __restrict__ traj, const unsigned short* __restrict__ Bf,
    const float* __restrict__ bconst, const float* __restrict__ f2seg, const float* __restrict__ f3seg,
    const float* __restrict__ ln_g, const float* __restrict__ ln_b, float* __restrict__ out){
  __shared__ float buf[16*1024];
  __shared__ float mu[16];
  __shared__ float rs[16];
  int t = blockIdx.x, tid = threadIdx.x, w = tid>>6, l = tid&63;
  const unsigned short* Ab = traj + ((size_t)t*16 + (l&15))*256 + (l>>4)*8;
  const s16x8* Bp = (const s16x8*)Bf;
  f32x4 z = {0.f,0.f,0.f,0.f};
  f32x4 ac[4]; ac[0]=z; ac[1]=z; ac[2]=z; ac[3]=z;
  #pragma unroll
  for (int kt=0;kt<8;kt++){
    s16x8 a = *(const s16x8*)(Ab + kt*32);
    #pragma unroll
    for (int i=0;i<4;i++){
      int nt = w*4+i;
      ac[i] = MFMA(a, Bp[((size_t)nt*8+kt)*64+l], ac[i]);
    }
  }
  int tc = t+1, s2 = tc>>4, s3 = tc>>7;
  int r0 = (l>>4)*4, cl = l&15;
  #pragma unroll
  for (int i=0;i<4;i++){
    int col = (w*4+i)*16+cl;
    #pragma unroll
    for (int j=0;j<4;j++){
      int b = r0+j;
      buf[b*1024+col] = ac[i][j] + bconst[col]
        + f2seg[((size_t)s2*16+b)*1024+col] + f3seg[((size_t)s3*16+b)*1024+col];
    }
  }
  __syncthreads();
  {
    float s=0.f, q=0.f;
    #pragma unroll
    for (int i=0;i<16;i++){ float xv = buf[w*1024 + l + 64*i]; s+=xv; q+=xv*xv; }
    #pragma unroll
    for (int off=32;off;off>>=1){ s += __shfl_down(s,off); q += __shfl_down(q,off); }
    if (l==0){ float m = s*(1.f/1024.f); float var = q*(1.f/1024.f) - m*m; mu[w]=m; rs[w]=rsqrtf(var+1e-5f); }
  }
  __syncthreads();
  {
    int b = tid>>6, d0 = tid&63;
    float m = mu[b], r = rs[b];
    size_t ob = ((size_t)b*1024 + t)*1024;
    #pragma unroll
    for (int i=0;i<16;i++){
      int d = d0 + 64*i;
      out[ob + d] = (buf[b*1024+d]-m)*r*ln_g[d] + ln_b[d];
    }
  }
}

// ---------------- launcher ----------------
extern "C" void kernel_launch(void* const* d_in, const int* in_sizes, int n_in,
                              void* d_out, int out_size, void* d_ws, size_t ws_size,
                              hipStream_t stream){
  const float* x     = (const float*)d_in[0];
  const float* w_t1g = (const float*)d_in[1];
  const float* b_t1g = (const float*)d_in[2];
  const float* w_t1c = (const float*)d_in[3];
  const float* b_t1c = (const float*)d_in[4];
  const float* w_t1r = (const float*)d_in[5];
  const float* b_t1r = (const float*)d_in[6];
  const float* w_t2v = (const float*)d_in[7];
  const float* b_t2v = (const float*)d_in[8];
  const float* w_t2b = (const float*)d_in[9];
  const float* b_t2b = (const float*)d_in[10];
  const float* w_t2r = (const float*)d_in[11];
  const float* b_t2r = (const float*)d_in[12];
  const float* w_t3o = (const float*)d_in[13];
  const float* b_t3o = (const float*)d_in[14];
  const float* w_t3n = (const float*)d_in[15];
  const float* b_t3n = (const float*)d_in[16];
  const float* w_t3r = (const float*)d_in[17];
  const float* b_t3r = (const float*)d_in[18];
  const float* w_b32 = (const float*)d_in[19];
  const float* b_b32 = (const float*)d_in[20];
  const float* w_b21 = (const float*)d_in[21];
  const float* b_b21 = (const float*)d_in[22];
  const float* w_fuse= (const float*)d_in[23];
  const float* b_fuse= (const float*)d_in[24];
  const float* ln_g  = (const float*)d_in[25];
  const float* ln_b  = (const float*)d_in[26];
  float* out = (float*)d_out;
  (void)in_sizes; (void)n_in; (void)out_size; (void)ws_size;

  char* base = (char*)d_ws;
  size_t off = 0;
  auto alloc = [&](size_t bytes) -> void* {
    void* p = base + off;
    off += (bytes + 255) & ~(size_t)255;
    return p;
  };
  unsigned short* xtb   = (unsigned short*)alloc((size_t)B_*T_*D_*2);
  float* Pg             = (float*)alloc((size_t)B_*T_*256*4);
  float* Pc             = (float*)alloc((size_t)B_*T_*256*4);
  unsigned short* traj1 = (unsigned short*)alloc((size_t)B_*T_*256*2);
  unsigned short* bm    = (unsigned short*)alloc((size_t)1024*1024*2);
  float* v      = (float*)alloc((size_t)1024*128*4);
  float* beta   = (float*)alloc(1024*4);
  float* wr1f   = (float*)alloc((size_t)256*1024*4);
  float* wr2f   = (float*)alloc((size_t)128*1024*4);
  float* wr3f   = (float*)alloc((size_t)128*1024*4);
  float* w2o    = (float*)alloc(128*64*4);
  float* w2n    = (float*)alloc(128*64*4);
  float* b2o    = (float*)alloc(64*4);
  float* b2n    = (float*)alloc(64*4);
  float* bconst = (float*)alloc(1024*4);
  unsigned short* t2traj = (unsigned short*)alloc((size_t)1040*128*2);
  unsigned short* t3traj = (unsigned short*)alloc((size_t)144*128*2);
  float* b21seg = (float*)alloc((size_t)1040*256*4);
  float* f2seg  = (float*)alloc((size_t)1040*1024*4);
  float* f3seg  = (float*)alloc((size_t)144*1024*4);
  unsigned short* w_t1r_bf = (unsigned short*)alloc((size_t)256*1024*2);
  unsigned short* w_t2r_bf = (unsigned short*)alloc((size_t)128*1024*2);
  unsigned short* w_t3r_bf = (unsigned short*)alloc((size_t)128*1024*2);
  unsigned short* wg1f  = (unsigned short*)alloc((size_t)1024*256*2);
  unsigned short* wg2f  = (unsigned short*)alloc((size_t)256*256*2);
  unsigned short* wc1f  = (unsigned short*)alloc((size_t)1024*256*2);
  unsigned short* wc2f  = (unsigned short*)alloc((size_t)256*256*2);
  unsigned short* wtvf  = (unsigned short*)alloc((size_t)1024*128*2);
  unsigned short* wb21f = (unsigned short*)alloc((size_t)128*256*2);
  unsigned short* wf1f  = (unsigned short*)alloc((size_t)1024*1024*2);
  unsigned short* wf2f  = (unsigned short*)alloc((size_t)1024*1024*2);
  unsigned short* wf3f  = (unsigned short*)alloc((size_t)1024*1024*2);
  unsigned short* w3of  = (unsigned short*)alloc((size_t)1024*64*2);
  unsigned short* w3nf  = (unsigned short*)alloc((size_t)1024*64*2);
  unsigned short* wr1ff = (unsigned short*)alloc((size_t)256*1024*2);
  unsigned short* wr2ff = (unsigned short*)alloc((size_t)128*1024*2);
  unsigned short* wr3ff = (unsigned short*)alloc((size_t)128*1024*2);

  // conversions / fragment packs
  k_conv_xtb<<<dim3(B_*T_), dim3(256), 0, stream>>>(x, xtb);
  k_conv<<<dim3(256), dim3(256), 0, stream>>>(w_t1r, w_t1r_bf, 256*1024);
  k_conv<<<dim3(128), dim3(256), 0, stream>>>(w_t2r, w_t2r_bf, 128*1024);
  k_conv<<<dim3(128), dim3(256), 0, stream>>>(w_t3r, w_t3r_bf, 128*1024);
  k_fragprep<<<dim3(128), dim3(256), 0, stream>>>(w_t1g, 0, 1024, 256, 256, wg1f);
  k_fragprep<<<dim3(32),  dim3(256), 0, stream>>>(w_t1g, 1024, 256, 256, 256, wg2f);
  k_fragprep<<<dim3(128), dim3(256), 0, stream>>>(w_t1c, 0, 1024, 256, 256, wc1f);
  k_fragprep<<<dim3(32),  dim3(256), 0, stream>>>(w_t1c, 1024, 256, 256, 256, wc2f);
  k_fragprep<<<dim3(64),  dim3(256), 0, stream>>>(w_t2v, 0, 1024, 128, 128, wtvf);
  k_fragprep<<<dim3(16),  dim3(256), 0, stream>>>(w_b21, 0, 128, 256, 256, wb21f);
  k_fragprep<<<dim3(512), dim3(256), 0, stream>>>(w_fuse, 0,    1024, 1024, 1024, wf1f);
  k_fragprep<<<dim3(512), dim3(256), 0, stream>>>(w_fuse, 1024, 1024, 1024, 1024, wf2f);
  k_fragprep<<<dim3(512), dim3(256), 0, stream>>>(w_fuse, 2048, 1024, 1024, 1024, wf3f);
  k_fragprep<<<dim3(32),  dim3(256), 0, stream>>>(w_t3o, 0, 1024, 64, 64, w3of);
  k_fragprep<<<dim3(32),  dim3(256), 0, stream>>>(w_t3n, 0, 1024, 64, 64, w3nf);
  // window means + beta
  k_bm<<<dim3(1024), dim3(256), 0, stream>>>(x, bm);
  k_beta<<<dim3(1024), dim3(64), 0, stream>>>(bm, w_t2b, b_t2b, beta);
  // parallel GEMMs
  k_gemm<<<dim3(4,256), dim3(256), 0, stream>>>(16384,256,1024, xtb,1024, wg1f, b_t1g, 0, Pg, 256);
  k_gemm<<<dim3(4,256), dim3(256), 0, stream>>>(16384,256,1024, xtb,1024, wc1f, b_t1c, 0, Pc, 256);
  k_gemm<<<dim3(2,16),  dim3(256), 0, stream>>>(1024,128,1024, bm,1024, wtvf, b_t2v, 0, v, 128);
  k_gemm<<<dim3(16,4),  dim3(256), 0, stream>>>(256,1024,1024, w_t1r_bf,1024, wf1f, nullptr, 0, wr1f, 1024);
  k_gemm<<<dim3(16,2),  dim3(256), 0, stream>>>(128,1024,1024, w_t2r_bf,1024, wf2f, nullptr, 0, wr2f, 1024);
  k_gemm<<<dim3(16,2),  dim3(256), 0, stream>>>(128,1024,1024, w_t3r_bf,1024, wf3f, nullptr, 0, wr3f, 1024);
  k_gemm<<<dim3(1,2),   dim3(256), 0, stream>>>(128,64,1024, w_t2r_bf,1024, w3of, nullptr, 0, w2o, 64);
  k_gemm<<<dim3(1,2),   dim3(256), 0, stream>>>(128,64,1024, w_t2r_bf,1024, w3nf, nullptr, 0, w2n, 64);
  // bias folds
  k_bconst<<<dim3(16), dim3(256), 0, stream>>>(w_fuse, b_fuse, b_t1r, b_t2r, b_t3r, bconst);
  k_b2<<<dim3(1), dim3(256), 0, stream>>>(b_t2r, w_t3o, b_t3o, w_t3n, b_t3n, b2o, b2n);
  // fragment packs of folded weights
  k_fragprep<<<dim3(128), dim3(256), 0, stream>>>(wr1f, 0, 256, 1024, 1024, wr1ff);
  k_fragprep<<<dim3(64),  dim3(256), 0, stream>>>(wr2f, 0, 128, 1024, 1024, wr2ff);
  k_fragprep<<<dim3(64),  dim3(256), 0, stream>>>(wr3f, 0, 128, 1024, 1024, wr3ff);
  // tier2/3 trajectory
  k_traj<<<dim3(1), dim3(1024), 0, stream>>>(v, beta, w_b32, b_b32, w2o, b2o, w2n, b2n, t2traj, t3traj);
  // segment GEMMs
  k_gemm<<<dim3(4,17),  dim3(256), 0, stream>>>(1040,256,128, t2traj,128, wb21f, b_b21, 1, b21seg, 256);
  k_gemm<<<dim3(16,17), dim3(256), 0, stream>>>(1040,1024,128, t2traj,128, wr2ff, nullptr, 0, f2seg, 1024);
  k_gemm<<<dim3(16,3),  dim3(256), 0, stream>>>(144,1024,128, t3traj,128, wr3ff, nullptr, 0, f3seg, 1024);
  // tier1 recurrence (critical path) — one block per batch row
  k_recur<<<dim3(16), dim3(512), 0, stream>>>(Pg, Pc, b21seg, wg2f, wc2f, traj1);
  // fused output + LN
  k_final<<<dim3(1024), dim3(1024), 0, stream>>>(traj1, wr1ff, bconst, f2seg, f3seg, ln_g, ln_b, out);
}